// Round 5
// baseline (234.573 us; speedup 1.0000x reference)
//
#include <hip/hip_runtime.h>

#define N_ROWS 8192
#define NX     4096
#define DIM    512
#define BT     128                    // block tile (rows & cols)
#define NT     64                     // N_ROWS / BT
#define NB     (NT * (NT + 1) / 2)    // 2080 live upper-triangle blocks
#define NGRP   512                    // 16-row groups
#define NCH    16                     // 32-wide k chunks

typedef __bf16 bf16_t;
typedef bf16_t bf16x8 __attribute__((ext_vector_type(8)));
typedef float  f32x4  __attribute__((ext_vector_type(4)));

#if __has_builtin(__builtin_amdgcn_exp2f)
  #define EXP2F __builtin_amdgcn_exp2f
#else
  #define EXP2F exp2f
#endif

// ws layout (bytes):
//   0       sqrow[8192]   float  (32768)   exact fp32 row norms
//   32768   colsum[512]   float  (2048)    zeroed by hipMemsetAsync
//   34816   cvals[5]      float  (20)
//   34848   acc           double (8)
//   34856   done          uint   (4)
//   36864   Zh2[8192*512] bf16   (8388608) FRAGMENT-TILED:
//     elem (row, k) at Zh2[((g*16 + C)*64 + l)*8 + j]
//     g=row>>4, C=k>>5, l=(row&15)|(((k>>3)&3)<<4), j=k&7
//     -> one MFMA A/B fragment (16 rows x 32 k) = contiguous 1 KB in lane order

__device__ __forceinline__ const float* zrow(const float* X, const float* Y, int r) {
    return (r < NX) ? (X + (size_t)r * DIM) : (Y + (size_t)(r - NX) * DIM);
}

// blocks [0,512): build Zh2 row-group + exact sqrow (LDS reduce)
// blocks [512,576): colsum partials via fp32 atomics (R1-proven cheap)
__global__ void k_prep(const float* __restrict__ X, const float* __restrict__ Y,
                       bf16_t* __restrict__ Zh2, float* __restrict__ sqrow,
                       float* __restrict__ colsum) {
    int t = threadIdx.x;
    if (blockIdx.x < NGRP) {
        int R = blockIdx.x;
        __shared__ float lsq[16];
        if (t < 16) lsq[t] = 0.f;
        __syncthreads();
        int C = t >> 4, u = t & 15;
        int rbase = 4 * (u & 3);           // row16 base for this thread
        int k = C * 32 + (u >> 2) * 8;     // 8 consecutive k
        int l0 = (4 * t) & 63;             // first lane-slot
        #pragma unroll
        for (int i = 0; i < 4; ++i) {
            int row = R * 16 + rbase + i;
            const float* zr = zrow(X, Y, row) + k;
            float4 va = *(const float4*)zr;
            float4 vb = *(const float4*)(zr + 4);
            bf16x8 h = {(bf16_t)va.x, (bf16_t)va.y, (bf16_t)va.z, (bf16_t)va.w,
                        (bf16_t)vb.x, (bf16_t)vb.y, (bf16_t)vb.z, (bf16_t)vb.w};
            *(bf16x8*)(Zh2 + ((size_t)(R * 16 + C) * 64 + (l0 + i)) * 8) = h;
            float d = va.x*va.x + va.y*va.y + va.z*va.z + va.w*va.w
                    + vb.x*vb.x + vb.y*vb.y + vb.z*vb.z + vb.w*vb.w;
            atomicAdd(&lsq[rbase + i], d);
        }
        __syncthreads();
        if (t < 16) sqrow[R * 16 + t] = lsq[t];
    } else {
        int b2 = blockIdx.x - NGRP;        // 0..63
        int c = t * 2;
        int r0 = b2 * 128;
        float s0 = 0.f, s1 = 0.f;
        for (int r = r0; r < r0 + 128; ++r) {
            float2 v = *(const float2*)(zrow(X, Y, r) + c);
            s0 += v.x; s1 += v.y;
        }
        atomicAdd(&colsum[c], s0);
        atomicAdd(&colsum[c + 1], s1);
    }
}

// bw = (2n*S1 - 2*||colsum||^2)/(n^2-n); cvals; zero acc/done
__global__ void k_bw(const float* __restrict__ sqrow, const float* __restrict__ colsum,
                     float* cvals, double* acc, unsigned* done) {
    __shared__ double red[256];
    int t = threadIdx.x;
    double s1 = 0.0;
    for (int i = t; i < N_ROWS; i += 256) s1 += (double)sqrow[i];
    double cs = 0.0;
    for (int d = t; d < DIM; d += 256) { double v = colsum[d]; cs += v * v; }
    red[t] = s1; __syncthreads();
    for (int off = 128; off > 0; off >>= 1) { if (t < off) red[t] += red[t + off]; __syncthreads(); }
    double S1 = red[0]; __syncthreads();
    red[t] = cs; __syncthreads();
    for (int off = 128; off > 0; off >>= 1) { if (t < off) red[t] += red[t + off]; __syncthreads(); }
    if (t == 0) {
        double CS = red[0];
        double n = (double)N_ROWS;
        double bw = (2.0 * n * S1 - 2.0 * CS) / (n * n - n);
        const double LOG2E = 1.4426950408889634;
        double mult = 0.25;
        for (int k = 0; k < 5; ++k) {
            cvals[k] = (float)(-LOG2E / (bw * mult));
            mult *= 2.0;
        }
        *acc = 0.0;
        *done = 0u;
    }
}

// Barrier-free K-loop: fragments loaded DIRECTLY from fragment-tiled global
// (each load = coalesced dwordx4 at base+lane*16). 2D grid, ti fastest
// (R3-proven L2 order). Register double-buffer; no LDS in the hot loop.
// Layouts (m89/m91): A[m=lane&15][k=(lane>>4)*8+j]; C/D col=lane&15,
// row=(lane>>4)*4+reg.
__global__ __launch_bounds__(256) void k_pair(const bf16_t* __restrict__ Zh2,
                                              const float* __restrict__ sqrow,
                                              const float* __restrict__ cvals,
                                              double* acc, unsigned* done,
                                              float* out) {
    int ti = blockIdx.x, tj = blockIdx.y;
    if (tj < ti) return;

    int t = threadIdx.x, lane = t & 63, wv = t >> 6;
    int wr = wv >> 1, wc = wv & 1;

    const bf16_t* pa[4]; const bf16_t* pb[4];
    #pragma unroll
    for (int aa = 0; aa < 4; ++aa)
        pa[aa] = Zh2 + (size_t)(ti * 8 + wr * 4 + aa) * (16 * 512) + lane * 8;
    #pragma unroll
    for (int bb = 0; bb < 4; ++bb)
        pb[bb] = Zh2 + (size_t)(tj * 8 + wc * 4 + bb) * (16 * 512) + lane * 8;

    f32x4 accf[4][4];
    #pragma unroll
    for (int a = 0; a < 4; ++a)
        #pragma unroll
        for (int b = 0; b < 4; ++b)
            accf[a][b] = (f32x4){0.f, 0.f, 0.f, 0.f};

    bf16x8 a[4], b[4], an[4], bn[4];
    #pragma unroll
    for (int aa = 0; aa < 4; ++aa) a[aa] = *(const bf16x8*)(pa[aa]);
    #pragma unroll
    for (int bb = 0; bb < 4; ++bb) b[bb] = *(const bf16x8*)(pb[bb]);

    #pragma unroll
    for (int C = 0; C < NCH; ++C) {
        if (C < NCH - 1) {
            #pragma unroll
            for (int aa = 0; aa < 4; ++aa) an[aa] = *(const bf16x8*)(pa[aa] + (C + 1) * 512);
            #pragma unroll
            for (int bb = 0; bb < 4; ++bb) bn[bb] = *(const bf16x8*)(pb[bb] + (C + 1) * 512);
        }
        #pragma unroll
        for (int aa = 0; aa < 4; ++aa)
            #pragma unroll
            for (int bb = 0; bb < 4; ++bb)
                accf[aa][bb] = __builtin_amdgcn_mfma_f32_16x16x32_bf16(
                    a[aa], b[bb], accf[aa][bb], 0, 0, 0);
        #pragma unroll
        for (int aa = 0; aa < 4; ++aa) a[aa] = an[aa];
        #pragma unroll
        for (int bb = 0; bb < 4; ++bb) b[bb] = bn[bb];
    }

    // epilogue: D2 -> 5-bandwidth RBF via squaring chain (c_k halves per k)
    float c4 = cvals[4];
    int n16 = lane & 15, q16 = lane >> 4;
    int i0 = ti * BT + wr * 64;
    int j0 = tj * BT + wc * 64;

    float sqi[4][4], sqj[4];
    #pragma unroll
    for (int aa = 0; aa < 4; ++aa)
        #pragma unroll
        for (int r = 0; r < 4; ++r)
            sqi[aa][r] = sqrow[i0 + 16 * aa + q16 * 4 + r];
    #pragma unroll
    for (int bb = 0; bb < 4; ++bb)
        sqj[bb] = sqrow[j0 + 16 * bb + n16];

    float s_local = 0.f;
    #pragma unroll
    for (int aa = 0; aa < 4; ++aa) {
        #pragma unroll
        for (int bb = 0; bb < 4; ++bb) {
            #pragma unroll
            for (int r = 0; r < 4; ++r) {
                float d2 = fmaf(-2.f, accf[aa][bb][r], sqi[aa][r] + sqj[bb]);
                d2 = fmaxf(d2, 0.f);
                float e4 = EXP2F(d2 * c4);       // smallest |c|
                float e3 = e4 * e4;
                float e2 = e3 * e3;
                float e1 = e2 * e2;
                float e0 = e1 * e1;
                s_local += e4 + e3 + e2 + e1 + e0;
            }
        }
    }
    #pragma unroll
    for (int off = 32; off > 0; off >>= 1) s_local += __shfl_down(s_local, off);
    __shared__ float wsum[4];
    if (lane == 0) wsum[wv] = s_local;
    __syncthreads();
    if (t == 0) {
        float bs = wsum[0] + wsum[1] + wsum[2] + wsum[3];
        double si = (ti < NT / 2) ? 1.0 : -1.0;
        double sj = (tj < NT / 2) ? 1.0 : -1.0;
        double w = si * sj * ((ti == tj) ? 1.0 : 2.0);
        atomicAdd(acc, w * (double)bs);
        __threadfence();
        unsigned old = atomicAdd(done, 1u);
        if (old == NB - 1) {
            __threadfence();
            double tot = atomicAdd(acc, 0.0);
            out[0] = (float)(tot / ((double)NX * (double)NX));
        }
    }
}

extern "C" void kernel_launch(void* const* d_in, const int* in_sizes, int n_in,
                              void* d_out, int out_size, void* d_ws, size_t ws_size,
                              hipStream_t stream) {
    const float* X = (const float*)d_in[0];
    const float* Y = (const float*)d_in[1];
    float* out = (float*)d_out;

    float*    sqrow  = (float*)d_ws;
    float*    colsum = (float*)((char*)d_ws + 32768);
    float*    cvals  = (float*)((char*)d_ws + 34816);
    double*   acc    = (double*)((char*)d_ws + 34848);
    unsigned* done   = (unsigned*)((char*)d_ws + 34856);
    bf16_t*   Zh2    = (bf16_t*)((char*)d_ws + 36864);

    hipMemsetAsync(colsum, 0, 512 * sizeof(float), stream);
    k_prep<<<NGRP + 64, 256, 0, stream>>>(X, Y, Zh2, sqrow, colsum);
    k_bw  <<<1, 256, 0, stream>>>(sqrow, colsum, cvals, acc, done);
    k_pair<<<dim3(NT, NT), 256, 0, stream>>>(Zh2, sqrow, cvals, acc, done, out);
}

// Round 6
// 183.728 us; speedup vs baseline: 1.2767x; 1.2767x over previous
//
#include <hip/hip_runtime.h>

#define N_ROWS 8192
#define NX     4096
#define DIM    512
#define BT     128                    // block tile (rows & cols)
#define NT     64                     // N_ROWS / BT
#define NB     (NT * (NT + 1) / 2)    // 2080 live upper-triangle blocks
#define BK     32                     // K elements per stage (64 B per row)

typedef __bf16 bf16_t;
typedef bf16_t bf16x8 __attribute__((ext_vector_type(8)));
typedef bf16_t bf16x4 __attribute__((ext_vector_type(4)));
typedef float  f32x4  __attribute__((ext_vector_type(4)));

#if __has_builtin(__builtin_amdgcn_exp2f)
  #define EXP2F __builtin_amdgcn_exp2f
#else
  #define EXP2F exp2f
#endif

// ws layout (bytes):
//   0       sqrow[8192]   float  (32768)   exact fp32 row norms
//   32768   colsum[512]   float  (2048)    zeroed by hipMemsetAsync
//   34816   cvals[5]      float  (20, pad 32)
//   34848   acc           double (8)
//   34856   done          uint   (4)
//   36864   Zh[8192*512]  bf16   (8388608) row-major bf16 of concat(X,Y)

__device__ __forceinline__ const float* zrow(const float* X, const float* Y, int r) {
    return (r < NX) ? (X + (size_t)r * DIM) : (Y + (size_t)(r - NX) * DIM);
}

__device__ __forceinline__ void gload_lds16(const bf16_t* g, bf16_t* l) {
    __builtin_amdgcn_global_load_lds(
        (__attribute__((address_space(1))) void*)(void*)(g),
        (__attribute__((address_space(3))) void*)(void*)(l), 16, 0, 0);
}

// blocks [0,2048): convert 4 rows to bf16 + exact fp32 row norms
// blocks [2048,2112): colsum partials over 128-row slab via fp32 atomics
__global__ void k_prep(const float* __restrict__ X, const float* __restrict__ Y,
                       bf16_t* __restrict__ Zh, float* __restrict__ sqrow,
                       float* __restrict__ colsum) {
    int t = threadIdx.x;
    if (blockIdx.x < 2048) {
        int wv = t >> 6, lane = t & 63;
        int row = blockIdx.x * 4 + wv;
        const float4* z4 = (const float4*)zrow(X, Y, row);
        float4 a = z4[lane], b = z4[lane + 64];
        bf16x4 ha = {(bf16_t)a.x, (bf16_t)a.y, (bf16_t)a.z, (bf16_t)a.w};
        bf16x4 hb = {(bf16_t)b.x, (bf16_t)b.y, (bf16_t)b.z, (bf16_t)b.w};
        *(bf16x4*)(Zh + (size_t)row * DIM + lane * 4) = ha;
        *(bf16x4*)(Zh + (size_t)row * DIM + 256 + lane * 4) = hb;
        float s = a.x*a.x + a.y*a.y + a.z*a.z + a.w*a.w
                + b.x*b.x + b.y*b.y + b.z*b.z + b.w*b.w;
        #pragma unroll
        for (int off = 32; off > 0; off >>= 1) s += __shfl_down(s, off);
        if (lane == 0) sqrow[row] = s;
    } else {
        int b2 = blockIdx.x - 2048;        // 0..63
        int c = t * 2;
        int r0 = b2 * 128;
        float s0 = 0.f, s1 = 0.f;
        for (int r = r0; r < r0 + 128; ++r) {
            float2 v = *(const float2*)(zrow(X, Y, r) + c);
            s0 += v.x; s1 += v.y;
        }
        atomicAdd(&colsum[c], s0);
        atomicAdd(&colsum[c + 1], s1);
    }
}

// bw = (2n*S1 - 2*||colsum||^2)/(n^2-n); cvals; zero acc/done
__global__ void k_bw(const float* __restrict__ sqrow, const float* __restrict__ colsum,
                     float* cvals, double* acc, unsigned* done) {
    __shared__ double red[256];
    int t = threadIdx.x;
    double s1 = 0.0;
    for (int i = t; i < N_ROWS; i += 256) s1 += (double)sqrow[i];
    double cs = 0.0;
    for (int d = t; d < DIM; d += 256) { double v = colsum[d]; cs += v * v; }
    red[t] = s1; __syncthreads();
    for (int off = 128; off > 0; off >>= 1) { if (t < off) red[t] += red[t + off]; __syncthreads(); }
    double S1 = red[0]; __syncthreads();
    red[t] = cs; __syncthreads();
    for (int off = 128; off > 0; off >>= 1) { if (t < off) red[t] += red[t + off]; __syncthreads(); }
    if (t == 0) {
        double CS = red[0];
        double n = (double)N_ROWS;
        double bw = (2.0 * n * S1 - 2.0 * CS) / (n * n - n);
        const double LOG2E = 1.4426950408889634;
        double mult = 0.25;
        for (int k = 0; k < 5; ++k) {
            cvals[k] = (float)(-LOG2E / (bw * mult));
            mult *= 2.0;
        }
        *acc = 0.0;
        *done = 0u;
    }
}

// 2D grid (R3-proven L2 order), 128x128 tile, DOUBLE-buffered LDS with ONE
// barrier/iter (loads drained at a barrier one full iteration later).
// global_load_lds width=16; XOR swizzle on the global side keeps frag
// ds_read_b128 conflict-free. 4 waves, each 64x64 via 4x4 grid of 16x16x32.
// Layouts (m89/m91): A[m=lane&15][k=(lane>>4)*8+j]; C/D col=lane&15,
// row=(lane>>4)*4+reg.
__global__ __launch_bounds__(256) void k_pair(const bf16_t* __restrict__ Zh,
                                              const float* __restrict__ sqrow,
                                              const float* __restrict__ cvals,
                                              double* acc, unsigned* done,
                                              float* out) {
    int ti = blockIdx.x, tj = blockIdx.y;
    if (tj < ti) return;

    __shared__ bf16_t As[2][4096];   // 2 x 8 KB
    __shared__ bf16_t Bs[2][4096];
    __shared__ float wsum[4];

    int t = threadIdx.x, lane = t & 63, wv = t >> 6;
    int wr = wv >> 1, wc = wv & 1;

    // staging chunks: c = h*256+t; row r=c>>2, phys slot sq=c&3 holds logical
    // chunk q = sq ^ ((r>>1)&3)  -> 64 B-coalesced per row, swizzled in LDS
    const bf16_t* gA[2]; const bf16_t* gB[2];
    int ldsoff[2];
    #pragma unroll
    for (int h = 0; h < 2; ++h) {
        int c = h * 256 + t;
        int r = c >> 2, sq = c & 3;
        int q = sq ^ ((r >> 1) & 3);
        gA[h] = Zh + (size_t)(ti * BT + r) * DIM + q * 8;
        gB[h] = Zh + (size_t)(tj * BT + r) * DIM + q * 8;
        ldsoff[h] = (h * 256 + wv * 64) * 8;    // wave-uniform base (lane*16B implicit)
    }

    // fragment LDS element offsets
    int n16 = lane & 15, q16 = lane >> 4;
    int aoff[4], boff[4];
    #pragma unroll
    for (int aa = 0; aa < 4; ++aa) {
        int r = 16 * (wr * 4 + aa) + n16;
        aoff[aa] = (r * 4 + (q16 ^ ((r >> 1) & 3))) * 8;
    }
    #pragma unroll
    for (int bb = 0; bb < 4; ++bb) {
        int r = 16 * (wc * 4 + bb) + n16;
        boff[bb] = (r * 4 + (q16 ^ ((r >> 1) & 3))) * 8;
    }

    f32x4 accf[4][4];
    #pragma unroll
    for (int a = 0; a < 4; ++a)
        #pragma unroll
        for (int b = 0; b < 4; ++b)
            accf[a][b] = (f32x4){0.f, 0.f, 0.f, 0.f};

    // prologue: stage buffer 0 (kt=0)
    #pragma unroll
    for (int h = 0; h < 2; ++h) {
        gload_lds16(gA[h], &As[0][ldsoff[h]]);
        gload_lds16(gB[h], &Bs[0][ldsoff[h]]);
    }

    for (int kt = 0; kt < DIM; kt += BK) {
        int cur = (kt >> 5) & 1;
        __syncthreads();   // drains cur-buf loads (issued one iteration ago)
        if (kt + BK < DIM) {
            #pragma unroll
            for (int h = 0; h < 2; ++h) {
                gload_lds16(gA[h] + kt + BK, &As[cur ^ 1][ldsoff[h]]);
                gload_lds16(gB[h] + kt + BK, &Bs[cur ^ 1][ldsoff[h]]);
            }
        }
        bf16x8 a[4], b[4];
        #pragma unroll
        for (int aa = 0; aa < 4; ++aa) a[aa] = *(const bf16x8*)(&As[cur][aoff[aa]]);
        #pragma unroll
        for (int bb = 0; bb < 4; ++bb) b[bb] = *(const bf16x8*)(&Bs[cur][boff[bb]]);
        #pragma unroll
        for (int aa = 0; aa < 4; ++aa)
            #pragma unroll
            for (int bb = 0; bb < 4; ++bb)
                accf[aa][bb] = __builtin_amdgcn_mfma_f32_16x16x32_bf16(
                    a[aa], b[bb], accf[aa][bb], 0, 0, 0);
    }

    // epilogue: D2 -> 5-bandwidth RBF via squaring chain (c_k halves per k)
    float c4 = cvals[4];
    int i0 = ti * BT + wr * 64;
    int j0 = tj * BT + wc * 64;

    float sqi[4][4], sqj[4];
    #pragma unroll
    for (int aa = 0; aa < 4; ++aa)
        #pragma unroll
        for (int r = 0; r < 4; ++r)
            sqi[aa][r] = sqrow[i0 + 16 * aa + q16 * 4 + r];
    #pragma unroll
    for (int bb = 0; bb < 4; ++bb)
        sqj[bb] = sqrow[j0 + 16 * bb + n16];

    float s_local = 0.f;
    #pragma unroll
    for (int aa = 0; aa < 4; ++aa) {
        #pragma unroll
        for (int bb = 0; bb < 4; ++bb) {
            #pragma unroll
            for (int r = 0; r < 4; ++r) {
                float d2 = fmaf(-2.f, accf[aa][bb][r], sqi[aa][r] + sqj[bb]);
                d2 = fmaxf(d2, 0.f);
                float e4 = EXP2F(d2 * c4);       // smallest |c|
                float e3 = e4 * e4;
                float e2 = e3 * e3;
                float e1 = e2 * e2;
                float e0 = e1 * e1;
                s_local += e4 + e3 + e2 + e1 + e0;
            }
        }
    }
    #pragma unroll
    for (int off = 32; off > 0; off >>= 1) s_local += __shfl_down(s_local, off);
    if (lane == 0) wsum[wv] = s_local;
    __syncthreads();
    if (t == 0) {
        float bs = wsum[0] + wsum[1] + wsum[2] + wsum[3];
        double si = (ti < NT / 2) ? 1.0 : -1.0;
        double sj = (tj < NT / 2) ? 1.0 : -1.0;
        double w = si * sj * ((ti == tj) ? 1.0 : 2.0);
        atomicAdd(acc, w * (double)bs);
        __threadfence();
        unsigned old = atomicAdd(done, 1u);
        if (old == NB - 1) {                      // last block finalizes
            __threadfence();
            double tot = atomicAdd(acc, 0.0);
            out[0] = (float)(tot / ((double)NX * (double)NX));
        }
    }
}

extern "C" void kernel_launch(void* const* d_in, const int* in_sizes, int n_in,
                              void* d_out, int out_size, void* d_ws, size_t ws_size,
                              hipStream_t stream) {
    const float* X = (const float*)d_in[0];
    const float* Y = (const float*)d_in[1];
    float* out = (float*)d_out;

    float*    sqrow  = (float*)d_ws;
    float*    colsum = (float*)((char*)d_ws + 32768);
    float*    cvals  = (float*)((char*)d_ws + 34816);
    double*   acc    = (double*)((char*)d_ws + 34848);
    unsigned* done   = (unsigned*)((char*)d_ws + 34856);
    bf16_t*   Zh     = (bf16_t*)((char*)d_ws + 36864);

    hipMemsetAsync(colsum, 0, 512 * sizeof(float), stream);
    k_prep<<<2112, 256, 0, stream>>>(X, Y, Zh, sqrow, colsum);
    k_bw  <<<1, 256, 0, stream>>>(sqrow, colsum, cvals, acc, done);
    k_pair<<<dim3(NT, NT), 256, 0, stream>>>(Zh, sqrow, cvals, acc, done, out);
}